// Round 2
// baseline (237.870 us; speedup 1.0000x reference)
//
#include <hip/hip_runtime.h>

// MCLLoss: masked L1 loss over 5 overlapping value-ranges of real_img.
// Ranges: (-1,1), (-1,-.5), (-.5,0), (0,.5), (.5,1) — inclusive bounds,
// masks overlap; class_mask takes the LAST matching range index.
// Output layout: [loss, losses[5], class_mask_rescaled[N]]; rescale = cls*0.5-1.
//
// R1: latency-bound fix — 8192 blocks (was 1024), 2x unrolled float4 loads
// issued before compute (64 B in flight/thread), accumulators padded to
// separate cache lines (256 B stride) to spread atomic traffic.

#define ACC_STRIDE 64  // floats between accumulators (256 B = 2 L2 lines apart)

__device__ __forceinline__ void proc_elem(float pv, float rv,
                                          float s[5], unsigned int c[5],
                                          float& ov) {
    float d = fabsf(pv - rv);
    bool geM1  = rv >= -1.0f;
    bool leM05 = rv <= -0.5f;
    bool geM05 = rv >= -0.5f;
    bool le0   = rv <=  0.0f;
    bool ge0   = rv >=  0.0f;
    bool le05  = rv <=  0.5f;
    bool ge05  = rv >=  0.5f;
    bool le1   = rv <=  1.0f;
    bool in0 = geM1  && le1;
    bool in1 = geM1  && leM05;
    bool in2 = geM05 && le0;
    bool in3 = ge0   && le05;
    bool in4 = ge05  && le1;
    s[0] += in0 ? d : 0.f;  c[0] += in0;
    s[1] += in1 ? d : 0.f;  c[1] += in1;
    s[2] += in2 ? d : 0.f;  c[2] += in2;
    s[3] += in3 ? d : 0.f;  c[3] += in3;
    s[4] += in4 ? d : 0.f;  c[4] += in4;
    int cls = in4 ? 4 : (in3 ? 3 : (in2 ? 2 : (in1 ? 1 : 0)));
    ov = 0.5f * (float)cls - 1.0f;
}

__global__ __launch_bounds__(256, 8) void mcl_main(
    const float* __restrict__ pre, const float* __restrict__ real,
    float* __restrict__ mask_out, float* __restrict__ sums,
    unsigned int* __restrict__ counts, int n4, int n)
{
    float s[5] = {0.f, 0.f, 0.f, 0.f, 0.f};
    unsigned int c[5] = {0u, 0u, 0u, 0u, 0u};

    const int t = threadIdx.x;
    // per-block contiguous chunk of 512 float4s (8 KB); two groups 256 apart
    const int i0 = blockIdx.x * 512 + t;
    const int i1 = i0 + 256;
    const bool v0 = i0 < n4;
    const bool v1 = i1 < n4;

    const float4* pre4  = (const float4*)pre;
    const float4* real4 = (const float4*)real;

    // issue all four 16B loads before any compute (64 B in flight/thread)
    float4 p0, r0, p1, r1;
    if (v0) { p0 = pre4[i0]; r0 = real4[i0]; }
    if (v1) { p1 = pre4[i1]; r1 = real4[i1]; }

    if (v0) {
        float ov[4];
        proc_elem(p0.x, r0.x, s, c, ov[0]);
        proc_elem(p0.y, r0.y, s, c, ov[1]);
        proc_elem(p0.z, r0.z, s, c, ov[2]);
        proc_elem(p0.w, r0.w, s, c, ov[3]);
        // mask_out = d_out+6: 8-byte aligned only -> float2 stores
        float2* mo = (float2*)(mask_out + 4 * (size_t)i0);
        mo[0] = make_float2(ov[0], ov[1]);
        mo[1] = make_float2(ov[2], ov[3]);
    }
    if (v1) {
        float ov[4];
        proc_elem(p1.x, r1.x, s, c, ov[0]);
        proc_elem(p1.y, r1.y, s, c, ov[1]);
        proc_elem(p1.z, r1.z, s, c, ov[2]);
        proc_elem(p1.w, r1.w, s, c, ov[3]);
        float2* mo = (float2*)(mask_out + 4 * (size_t)i1);
        mo[0] = make_float2(ov[0], ov[1]);
        mo[1] = make_float2(ov[2], ov[3]);
    }

    // scalar tail (n not divisible by 4)
    {
        int tail_base = n4 * 4;
        int tail = n - tail_base;
        int gtid = blockIdx.x * blockDim.x + t;
        if (gtid < tail) {
            int idx = tail_base + gtid;
            float ov;
            proc_elem(pre[idx], real[idx], s, c, ov);
            mask_out[idx] = ov;
        }
    }

    // wave64 butterfly reduction
#pragma unroll
    for (int j = 0; j < 5; ++j) {
#pragma unroll
        for (int off = 32; off > 0; off >>= 1) {
            s[j] += __shfl_down(s[j], off, 64);
            c[j] += __shfl_down(c[j], off, 64);
        }
    }

    __shared__ float ls[4][5];
    __shared__ unsigned int lc[4][5];
    int lane = t & 63;
    int wave = t >> 6;
    if (lane == 0) {
#pragma unroll
        for (int j = 0; j < 5; ++j) { ls[wave][j] = s[j]; lc[wave][j] = c[j]; }
    }
    __syncthreads();
    if (t < 5) {
        float ssum = ls[0][t] + ls[1][t] + ls[2][t] + ls[3][t];
        unsigned int csum = lc[0][t] + lc[1][t] + lc[2][t] + lc[3][t];
        atomicAdd(&sums[t * ACC_STRIDE], ssum);
        atomicAdd(&counts[t * ACC_STRIDE], csum);
    }
}

__global__ void mcl_final(const float* __restrict__ sums,
                          const unsigned int* __restrict__ counts,
                          float* __restrict__ out)
{
    if (threadIdx.x == 0) {
        float total = 0.f;
        float losses[5];
#pragma unroll
        for (int j = 0; j < 5; ++j) {
            unsigned int cnt = counts[j * ACC_STRIDE];
            unsigned int denom = cnt > 1u ? cnt : 1u;
            float l = (cnt == 0u) ? 0.f : (sums[j * ACC_STRIDE] / (float)denom) * 0.2f;
            losses[j] = l;
            total += l;
        }
        out[0] = total;
#pragma unroll
        for (int j = 0; j < 5; ++j) out[1 + j] = losses[j];
    }
}

extern "C" void kernel_launch(void* const* d_in, const int* in_sizes, int n_in,
                              void* d_out, int out_size, void* d_ws, size_t ws_size,
                              hipStream_t stream) {
    const float* pre  = (const float*)d_in[0];
    const float* real = (const float*)d_in[1];
    float* out = (float*)d_out;
    int n = in_sizes[0];
    int n4 = n / 4;

    float* sums = (float*)d_ws;                                    // 5 @ stride 64 floats
    unsigned int* counts = (unsigned int*)d_ws + 5 * ACC_STRIDE;   // 5 @ stride 64

    // d_ws re-poisoned to 0xAA before every timed call — zero each launch.
    hipMemsetAsync(d_ws, 0, 10 * ACC_STRIDE * sizeof(float), stream);

    int blocks = (n4 + 511) / 512;                 // 8192 for N=16M
    if (blocks < 1) blocks = 1;
    mcl_main<<<blocks, 256, 0, stream>>>(pre, real, out + 6, sums, counts, n4, n);
    mcl_final<<<1, 64, 0, stream>>>(sums, counts, out);
}

// Round 4
// 183.984 us; speedup vs baseline: 1.2929x; 1.2929x over previous
//
#include <hip/hip_runtime.h>

// MCLLoss: masked L1 loss over 5 overlapping value-ranges of real_img.
// Ranges: (-1,1), (-1,-.5), (-.5,0), (0,.5), (.5,1) — inclusive bounds,
// masks overlap; class_mask takes the LAST matching range index.
// Output layout: [loss, losses[5], class_mask_rescaled[N]]; rescale = cls*0.5-1.
//
// R2/R3: 2048 blocks (8 blocks/CU resident via __launch_bounds__(256,8)),
// 8 float4 pairs per thread (epilogue amortized 8x), 2-deep manual load
// pipeline, nontemporal mask stores (native ext_vector_type for the builtin).

#define ACC_STRIDE 64  // floats between accumulators (256 B apart)
#define G_PER_T 8      // float4 groups per thread
#define BLK_F4 (256 * G_PER_T)  // 2048 float4 per block

typedef float fvec2 __attribute__((ext_vector_type(2)));  // native vec for nontemporal builtin

__device__ __forceinline__ void proc_elem(float pv, float rv,
                                          float s[5], unsigned int c[5],
                                          float& ov) {
    float d = fabsf(pv - rv);
    bool geM1  = rv >= -1.0f;
    bool leM05 = rv <= -0.5f;
    bool geM05 = rv >= -0.5f;
    bool le0   = rv <=  0.0f;
    bool ge0   = rv >=  0.0f;
    bool le05  = rv <=  0.5f;
    bool ge05  = rv >=  0.5f;
    bool le1   = rv <=  1.0f;
    bool in0 = geM1  && le1;
    bool in1 = geM1  && leM05;
    bool in2 = geM05 && le0;
    bool in3 = ge0   && le05;
    bool in4 = ge05  && le1;
    s[0] += in0 ? d : 0.f;  c[0] += in0;
    s[1] += in1 ? d : 0.f;  c[1] += in1;
    s[2] += in2 ? d : 0.f;  c[2] += in2;
    s[3] += in3 ? d : 0.f;  c[3] += in3;
    s[4] += in4 ? d : 0.f;  c[4] += in4;
    int cls = in4 ? 4 : (in3 ? 3 : (in2 ? 2 : (in1 ? 1 : 0)));
    ov = 0.5f * (float)cls - 1.0f;
}

__device__ __forceinline__ void proc_group(int i, const float4& p, const float4& r,
                                           float s[5], unsigned int c[5],
                                           float* __restrict__ mask_out) {
    float ov[4];
    proc_elem(p.x, r.x, s, c, ov[0]);
    proc_elem(p.y, r.y, s, c, ov[1]);
    proc_elem(p.z, r.z, s, c, ov[2]);
    proc_elem(p.w, r.w, s, c, ov[3]);
    // mask_out = d_out+6: 8-byte aligned only -> 8B stores; streaming
    // (never re-read) -> nontemporal to spare L2 for the read stream.
    fvec2* mo = (fvec2*)(mask_out + 4 * (size_t)i);
    fvec2 lo = {ov[0], ov[1]};
    fvec2 hi = {ov[2], ov[3]};
    __builtin_nontemporal_store(lo, mo);
    __builtin_nontemporal_store(hi, mo + 1);
}

__global__ __launch_bounds__(256, 8) void mcl_main(
    const float* __restrict__ pre, const float* __restrict__ real,
    float* __restrict__ mask_out, float* __restrict__ sums,
    unsigned int* __restrict__ counts, int n4, int n)
{
    float s[5] = {0.f, 0.f, 0.f, 0.f, 0.f};
    unsigned int c[5] = {0u, 0u, 0u, 0u, 0u};

    const int t = threadIdx.x;
    const int base = blockIdx.x * BLK_F4 + t;  // 8 chunks of 256 float4
    const float4* pre4  = (const float4*)pre;
    const float4* real4 = (const float4*)real;

    // 2-deep software pipeline over 4 iterations of 2 groups each:
    // loads for groups (k, k+1) in flight while computing (k-2, k-1).
    int ia = base, ib = base + 256;
    bool va = ia < n4, vb = ib < n4;
    float4 pa, ra, pb, rb;
    if (va) { pa = pre4[ia]; ra = real4[ia]; }
    if (vb) { pb = pre4[ib]; rb = real4[ib]; }

#pragma unroll
    for (int k = 0; k < G_PER_T / 2; ++k) {
        int ja = base + (2 * k + 2) * 256;
        int jb = ja + 256;
        bool nva = (k + 1 < G_PER_T / 2) && (ja < n4);
        bool nvb = (k + 1 < G_PER_T / 2) && (jb < n4);
        float4 npa, nra, npb, nrb;
        if (nva) { npa = pre4[ja]; nra = real4[ja]; }
        if (nvb) { npb = pre4[jb]; nrb = real4[jb]; }

        if (va) proc_group(ia, pa, ra, s, c, mask_out);
        if (vb) proc_group(ib, pb, rb, s, c, mask_out);

        ia = ja; ib = jb; va = nva; vb = nvb;
        pa = npa; ra = nra; pb = npb; rb = nrb;
    }

    // scalar tail (n not divisible by 4)
    {
        int tail_base = n4 * 4;
        int tail = n - tail_base;
        int gtid = blockIdx.x * blockDim.x + t;
        if (gtid < tail) {
            int idx = tail_base + gtid;
            float ov;
            proc_elem(pre[idx], real[idx], s, c, ov);
            mask_out[idx] = ov;
        }
    }

    // wave64 butterfly reduction (amortized over 8 float4/thread now)
#pragma unroll
    for (int j = 0; j < 5; ++j) {
#pragma unroll
        for (int off = 32; off > 0; off >>= 1) {
            s[j] += __shfl_down(s[j], off, 64);
            c[j] += __shfl_down(c[j], off, 64);
        }
    }

    __shared__ float ls[4][5];
    __shared__ unsigned int lc[4][5];
    int lane = t & 63;
    int wave = t >> 6;
    if (lane == 0) {
#pragma unroll
        for (int j = 0; j < 5; ++j) { ls[wave][j] = s[j]; lc[wave][j] = c[j]; }
    }
    __syncthreads();
    if (t < 5) {
        float ssum = ls[0][t] + ls[1][t] + ls[2][t] + ls[3][t];
        unsigned int csum = lc[0][t] + lc[1][t] + lc[2][t] + lc[3][t];
        atomicAdd(&sums[t * ACC_STRIDE], ssum);
        atomicAdd(&counts[t * ACC_STRIDE], csum);
    }
}

__global__ void mcl_final(const float* __restrict__ sums,
                          const unsigned int* __restrict__ counts,
                          float* __restrict__ out)
{
    if (threadIdx.x == 0) {
        float total = 0.f;
        float losses[5];
#pragma unroll
        for (int j = 0; j < 5; ++j) {
            unsigned int cnt = counts[j * ACC_STRIDE];
            unsigned int denom = cnt > 1u ? cnt : 1u;
            float l = (cnt == 0u) ? 0.f : (sums[j * ACC_STRIDE] / (float)denom) * 0.2f;
            losses[j] = l;
            total += l;
        }
        out[0] = total;
#pragma unroll
        for (int j = 0; j < 5; ++j) out[1 + j] = losses[j];
    }
}

extern "C" void kernel_launch(void* const* d_in, const int* in_sizes, int n_in,
                              void* d_out, int out_size, void* d_ws, size_t ws_size,
                              hipStream_t stream) {
    const float* pre  = (const float*)d_in[0];
    const float* real = (const float*)d_in[1];
    float* out = (float*)d_out;
    int n = in_sizes[0];
    int n4 = n / 4;

    float* sums = (float*)d_ws;                                    // 5 @ stride 64 floats
    unsigned int* counts = (unsigned int*)d_ws + 5 * ACC_STRIDE;   // 5 @ stride 64

    // d_ws re-poisoned to 0xAA before every timed call — zero each launch.
    (void)hipMemsetAsync(d_ws, 0, 10 * ACC_STRIDE * sizeof(float), stream);

    int blocks = (n4 + BLK_F4 - 1) / BLK_F4;       // 2048 for N=16M
    if (blocks < 1) blocks = 1;
    mcl_main<<<blocks, 256, 0, stream>>>(pre, real, out + 6, sums, counts, n4, n);
    mcl_final<<<1, 64, 0, stream>>>(sums, counts, out);
}

// Round 5
// 174.982 us; speedup vs baseline: 1.3594x; 1.0514x over previous
//
#include <hip/hip_runtime.h>

// MCLLoss: masked L1 loss over 5 overlapping value-ranges of real_img.
// Ranges: (-1,1), (-1,-.5), (-.5,0), (0,.5), (.5,1) — inclusive bounds,
// masks overlap; class_mask takes the LAST matching range index.
// Output layout: [loss, losses[5], class_mask_rescaled[N]]; rescale = cls*0.5-1.
//
// R5: atomic-serialization fix. R2's 8192-block shape (2 float4/thread, all
// loads upfront = max memory-level parallelism) regressed because every block
// fired 10 atomics at the SAME 10 addresses (chain depth 8192 x ~30cy ≈ 100us).
// Now: 64 accumulator banks (blockIdx&63, one 64B line each) -> depth 128;
// final kernel reduces banks with one wave of shuffles.

#define N_BANKS 64
#define BANK_F  16   // floats per bank (64 B line): sums at [0..4], counts at [8..12]

__device__ __forceinline__ void proc_elem(float pv, float rv,
                                          float s[5], unsigned int c[5],
                                          float& ov) {
    float d = fabsf(pv - rv);
    bool geM1  = rv >= -1.0f;
    bool leM05 = rv <= -0.5f;
    bool geM05 = rv >= -0.5f;
    bool le0   = rv <=  0.0f;
    bool ge0   = rv >=  0.0f;
    bool le05  = rv <=  0.5f;
    bool ge05  = rv >=  0.5f;
    bool le1   = rv <=  1.0f;
    bool in0 = geM1  && le1;
    bool in1 = geM1  && leM05;
    bool in2 = geM05 && le0;
    bool in3 = ge0   && le05;
    bool in4 = ge05  && le1;
    s[0] += in0 ? d : 0.f;  c[0] += in0;
    s[1] += in1 ? d : 0.f;  c[1] += in1;
    s[2] += in2 ? d : 0.f;  c[2] += in2;
    s[3] += in3 ? d : 0.f;  c[3] += in3;
    s[4] += in4 ? d : 0.f;  c[4] += in4;
    int cls = in4 ? 4 : (in3 ? 3 : (in2 ? 2 : (in1 ? 1 : 0)));
    ov = 0.5f * (float)cls - 1.0f;
}

__device__ __forceinline__ void proc_group(int i, const float4& p, const float4& r,
                                           float s[5], unsigned int c[5],
                                           float* __restrict__ mask_out) {
    float ov[4];
    proc_elem(p.x, r.x, s, c, ov[0]);
    proc_elem(p.y, r.y, s, c, ov[1]);
    proc_elem(p.z, r.z, s, c, ov[2]);
    proc_elem(p.w, r.w, s, c, ov[3]);
    // mask_out = d_out+6: 8-byte aligned only -> float2 stores
    float2* mo = (float2*)(mask_out + 4 * (size_t)i);
    mo[0] = make_float2(ov[0], ov[1]);
    mo[1] = make_float2(ov[2], ov[3]);
}

__global__ __launch_bounds__(256, 8) void mcl_main(
    const float* __restrict__ pre, const float* __restrict__ real,
    float* __restrict__ mask_out, float* __restrict__ acc, int n4, int n)
{
    float s[5] = {0.f, 0.f, 0.f, 0.f, 0.f};
    unsigned int c[5] = {0u, 0u, 0u, 0u, 0u};

    const int t = threadIdx.x;
    const int i0 = blockIdx.x * 512 + t;   // block covers 512 float4 (8 KB)
    const int i1 = i0 + 256;
    const bool v0 = i0 < n4;
    const bool v1 = i1 < n4;

    const float4* pre4  = (const float4*)pre;
    const float4* real4 = (const float4*)real;

    // all four 16B loads upfront: 64 B in flight per thread for the block's
    // whole life -> maximal device-wide memory-level parallelism
    float4 p0, r0, p1, r1;
    if (v0) { p0 = pre4[i0]; r0 = real4[i0]; }
    if (v1) { p1 = pre4[i1]; r1 = real4[i1]; }

    if (v0) proc_group(i0, p0, r0, s, c, mask_out);
    if (v1) proc_group(i1, p1, r1, s, c, mask_out);

    // scalar tail (n not divisible by 4)
    {
        int tail_base = n4 * 4;
        int tail = n - tail_base;
        int gtid = blockIdx.x * blockDim.x + t;
        if (gtid < tail) {
            int idx = tail_base + gtid;
            float ov;
            proc_elem(pre[idx], real[idx], s, c, ov);
            mask_out[idx] = ov;
        }
    }

    // wave64 butterfly reduction
#pragma unroll
    for (int j = 0; j < 5; ++j) {
#pragma unroll
        for (int off = 32; off > 0; off >>= 1) {
            s[j] += __shfl_down(s[j], off, 64);
            c[j] += __shfl_down(c[j], off, 64);
        }
    }

    __shared__ float ls[4][5];
    __shared__ unsigned int lc[4][5];
    int lane = t & 63;
    int wave = t >> 6;
    if (lane == 0) {
#pragma unroll
        for (int j = 0; j < 5; ++j) { ls[wave][j] = s[j]; lc[wave][j] = c[j]; }
    }
    __syncthreads();
    if (t < 5) {
        float ssum = ls[0][t] + ls[1][t] + ls[2][t] + ls[3][t];
        unsigned int csum = lc[0][t] + lc[1][t] + lc[2][t] + lc[3][t];
        float* bank = acc + (blockIdx.x & (N_BANKS - 1)) * BANK_F;
        atomicAdd(&bank[t], ssum);                        // sums at [0..4]
        atomicAdd((unsigned int*)bank + 8 + t, csum);     // counts at [8..12]
    }
}

__global__ void mcl_final(const float* __restrict__ acc, float* __restrict__ out)
{
    // one wave: lane l owns bank l, butterfly-reduce the 10 values
    int l = threadIdx.x;
    const float* bank = acc + l * BANK_F;
    float s[5];
    unsigned int c[5];
#pragma unroll
    for (int j = 0; j < 5; ++j) {
        s[j] = bank[j];
        c[j] = ((const unsigned int*)bank)[8 + j];
    }
#pragma unroll
    for (int j = 0; j < 5; ++j) {
#pragma unroll
        for (int off = 32; off > 0; off >>= 1) {
            s[j] += __shfl_down(s[j], off, 64);
            c[j] += __shfl_down(c[j], off, 64);
        }
    }
    if (l == 0) {
        float total = 0.f;
#pragma unroll
        for (int j = 0; j < 5; ++j) {
            unsigned int cnt = c[j];
            unsigned int denom = cnt > 1u ? cnt : 1u;
            float lv = (cnt == 0u) ? 0.f : (s[j] / (float)denom) * 0.2f;
            out[1 + j] = lv;
            total += lv;
        }
        out[0] = total;
    }
}

extern "C" void kernel_launch(void* const* d_in, const int* in_sizes, int n_in,
                              void* d_out, int out_size, void* d_ws, size_t ws_size,
                              hipStream_t stream) {
    const float* pre  = (const float*)d_in[0];
    const float* real = (const float*)d_in[1];
    float* out = (float*)d_out;
    int n = in_sizes[0];
    int n4 = n / 4;

    float* acc = (float*)d_ws;  // 64 banks x 16 floats = 4 KB

    // d_ws re-poisoned to 0xAA before every timed call — zero each launch.
    (void)hipMemsetAsync(d_ws, 0, N_BANKS * BANK_F * sizeof(float), stream);

    int blocks = (n4 + 511) / 512;                 // 8192 for N=16M
    if (blocks < 1) blocks = 1;
    mcl_main<<<blocks, 256, 0, stream>>>(pre, real, out + 6, acc, n4, n);
    mcl_final<<<1, 64, 0, stream>>>(acc, out);
}